// Round 1
// baseline (1010.636 us; speedup 1.0000x reference)
//
#include <hip/hip_runtime.h>

typedef unsigned long long u64;

#define THR 0.5f

// Convert one cxcywh box to ltrb + area, with FP contraction OFF so every op
// matches numpy's rn-per-op semantics bit-exactly (needed for the NMS >= 0.5
// predicate; a fused cx - 0.5*w -> fma differs in the last ulp).
__device__ __forceinline__ void conv_box(const float4 b, float& l, float& t,
                                         float& r, float& bo, float& a) {
  #pragma clang fp contract(off)
  float hw = 0.5f * b.z;
  float hh = 0.5f * b.w;
  l = b.x - hw;
  t = b.y - hh;
  r = b.x + hw;
  bo = b.y + hh;
  a = (r - l) * (bo - t);
}

__global__ void k_zero(int* __restrict__ rank, int n) {
  int i = blockIdx.x * blockDim.x + threadIdx.x;
  if (i < n) rank[i] = 0;
}

// Stable descending rank: rank[i] = #{j: s[j] > s[i]} + #{j < i: s[j] == s[i]}
// (== stable argsort(-scores) position). Partial j-ranges accumulated with
// integer atomics (deterministic sum).
__global__ void k_rank(const float* __restrict__ scores, int* __restrict__ rank,
                       int n, int jchunk) {
  int i = blockIdx.x * blockDim.x + threadIdx.x;
  if (i >= n) return;
  float si = scores[i];
  int j0 = blockIdx.y * jchunk;
  int j1 = min(j0 + jchunk, n);
  int c = 0;
  for (int j = j0; j < j1; ++j) {
    float sj = scores[j];
    c += ((sj > si) || (sj == si && j < i)) ? 1 : 0;
  }
  if (c) atomicAdd(rank + i, c);
}

__global__ void k_scatter(const float4* __restrict__ boxes, const int* __restrict__ rank,
                          float* __restrict__ sl, float* __restrict__ st,
                          float* __restrict__ sr, float* __restrict__ sb,
                          float* __restrict__ sa, int* __restrict__ sidx, int n) {
  int i = blockIdx.x * blockDim.x + threadIdx.x;
  if (i >= n) return;
  float l, t, r, b, a;
  conv_box(boxes[i], l, t, r, b, a);
  int k = rank[i];
  sl[k] = l; st[k] = t; sr[k] = r; sb[k] = b; sa[k] = a; sidx[k] = i;
}

// mask[k][w] bit b (j = w*64+b) set iff j>k, j<n, iou_nms(k,j) >= 0.5.
// NOTE: reference does NOT clamp the intersection here — replicate exactly,
// with contraction off and strict IEEE f32 division.
__global__ void k_mask(const float* __restrict__ sl, const float* __restrict__ st,
                       const float* __restrict__ sr, const float* __restrict__ sb,
                       const float* __restrict__ sa,
                       u64* __restrict__ mask, u64* __restrict__ diag,
                       int n, int wstride) {
  #pragma clang fp contract(off)
  int k = blockIdx.x * blockDim.x + threadIdx.x;
  if (k >= n) return;
  int w = blockIdx.y;
  int jbase = w << 6;
  u64 word = 0;
  if (jbase + 63 > k) {  // at least one j > k in this word
    float l = sl[k], t = st[k], r = sr[k], b = sb[k], a = sa[k];
    int jend = min(jbase + 64, n);
    for (int j = max(jbase, k + 1); j < jend; ++j) {
      float lmax = fmaxf(l, sl[j]);
      float tmax = fmaxf(t, st[j]);
      float rmin = fminf(r, sr[j]);
      float bmin = fminf(b, sb[j]);
      float wd = rmin - lmax;
      float hd = bmin - tmax;
      float inter = wd * hd;               // no clamp (matches reference NMS path)
      float denom = (a + sa[j]) - inter;
      float q = inter / denom;             // IEEE f32 div, same op order as numpy
      if (q >= THR) word |= 1ull << (j - jbase);
    }
  }
  mask[(size_t)k * wstride + w] = word;
  if ((k >> 6) == w) diag[k] = word;       // contiguous diagonal words for the scan
}

// Greedy serial NMS scan — single wave. Cross-group suppression state in LDS
// (157 words, lane l owns words l, l+64, l+128). Within a group, the 64-step
// serial chain runs on replicated registers only: all lanes preload the 64
// contiguous diagonal words (full unroll -> static indices -> registers).
__global__ __launch_bounds__(64, 1) void k_scan(const u64* __restrict__ mask,
                                                const u64* __restrict__ diag,
                                                const int* __restrict__ sidx,
                                                float* __restrict__ keep,
                                                int n, int wstride) {
  int lane = threadIdx.x;
  __shared__ u64 rem[192];
  rem[lane] = 0; rem[lane + 64] = 0; rem[lane + 128] = 0;
  __syncthreads();
  int ng = (n + 63) >> 6;
  for (int g = 0; g < ng; ++g) {
    u64 s = rem[g];                       // broadcast LDS read
    int base = g << 6;
    int valid = n - base;
    if (valid < 64) s |= (~0ull) << valid;  // nonexistent boxes = suppressed
    u64 d[64];
    #pragma unroll
    for (int b = 0; b < 64; ++b) d[b] = diag[base + b];
    u64 kw = 0;
    #pragma unroll
    for (int b = 0; b < 64; ++b) {
      if (!((s >> b) & 1ull)) { kw |= 1ull << b; s |= d[b]; }
    }
    // scatter keep flags (sorted -> original order)
    int k = base + lane;
    if (k < n) keep[sidx[k]] = ((kw >> lane) & 1ull) ? 1.0f : 0.0f;
    // fold kept rows into future-group suppression state
    u64 a0 = 0, a1 = 0, a2 = 0;
    u64 kk = kw;
    while (kk) {
      int b = __ffsll((long long)kk) - 1;
      kk &= kk - 1;
      const u64* row = mask + (size_t)(base + b) * wstride;
      a0 |= row[lane];
      if (lane + 64 < ng) a1 |= row[lane + 64];
      if (lane + 128 < ng) a2 |= row[lane + 128];
    }
    rem[lane] |= a0;
    rem[lane + 64] |= a1;
    rem[lane + 128] |= a2;
  }
}

// Pairwise IoU, original order, WITH clamp. Loose 2e-2 threshold -> fast rcp.
__device__ __forceinline__ float iou_one(float li, float ti, float ri, float bi, float ai,
                                         float lj, float tj, float rj, float bj, float aj) {
  float lmax = fmaxf(li, lj);
  float tmax = fmaxf(ti, tj);
  float rmin = fminf(ri, rj);
  float bmin = fminf(bi, bj);
  float w = fmaxf(rmin - lmax, 0.0f);
  float h = fmaxf(bmin - tmax, 0.0f);
  float inter = w * h;
  float denom = (ai + aj) - inter;
  return inter * __builtin_amdgcn_rcpf(denom);
}

__global__ void k_iou(const float4* __restrict__ boxes, float* __restrict__ out,
                      int n, int rpb) {
  int nj4 = (n + 3) >> 2;
  int j4 = blockIdx.x * blockDim.x + threadIdx.x;
  if (j4 >= nj4) return;
  int j = j4 << 2;
  int jc1 = min(j + 1, n - 1), jc2 = min(j + 2, n - 1), jc3 = min(j + 3, n - 1);
  float l0,t0,r0,b0,a0, l1,t1,r1,b1,a1, l2,t2,r2,b2,a2, l3,t3,r3,b3,a3;
  conv_box(boxes[j],   l0,t0,r0,b0,a0);
  conv_box(boxes[jc1], l1,t1,r1,b1,a1);
  conv_box(boxes[jc2], l2,t2,r2,b2,a2);
  conv_box(boxes[jc3], l3,t3,r3,b3,a3);
  bool full = (j + 3) < n;
  for (int rr = 0; rr < rpb; ++rr) {
    int i = blockIdx.y * rpb + rr;
    if (i >= n) return;
    float li,ti,ri,bi,ai;
    conv_box(boxes[i], li,ti,ri,bi,ai);
    float4 o;
    o.x = iou_one(li,ti,ri,bi,ai, l0,t0,r0,b0,a0);
    o.y = iou_one(li,ti,ri,bi,ai, l1,t1,r1,b1,a1);
    o.z = iou_one(li,ti,ri,bi,ai, l2,t2,r2,b2,a2);
    o.w = iou_one(li,ti,ri,bi,ai, l3,t3,r3,b3,a3);
    size_t row = (size_t)i * n;
    if (full) {
      *reinterpret_cast<float4*>(out + row + j) = o;
    } else {
      out[row + j] = o.x;
      if (j + 1 < n) out[row + j + 1] = o.y;
      if (j + 2 < n) out[row + j + 2] = o.z;
    }
  }
}

extern "C" void kernel_launch(void* const* d_in, const int* in_sizes, int n_in,
                              void* d_out, int out_size, void* d_ws, size_t ws_size,
                              hipStream_t stream) {
  const float* boxes = (const float*)d_in[0];
  const float* scores = (const float*)d_in[1];
  int n = in_sizes[1];
  float* out = (float*)d_out;
  size_t NN = (size_t)n * (size_t)n;
  float* keep = out + NN;

  int words = (n + 63) >> 6;
  int wstride = (words + 3) & ~3;   // pad row stride for 16B alignment
  // All scratch lives in the front of the IoU region of d_out; it is fully
  // consumed by k_scan before k_iou (launched last) overwrites it.
  char* base = (char*)d_out;
  size_t off = 0;
  u64* mask = (u64*)(base + off); off += (size_t)n * wstride * 8;
  u64* diag = (u64*)(base + off); off += (size_t)words * 64 * 8;
  off = (off + 255) & ~(size_t)255;
  float* sl  = (float*)(base + off); off += (size_t)n * 4;
  float* st_ = (float*)(base + off); off += (size_t)n * 4;
  float* sr  = (float*)(base + off); off += (size_t)n * 4;
  float* sb  = (float*)(base + off); off += (size_t)n * 4;
  float* sa  = (float*)(base + off); off += (size_t)n * 4;
  int* sidx  = (int*)(base + off); off += (size_t)n * 4;
  int* rank  = (int*)(base + off); off += (size_t)n * 4;

  int nb = (n + 255) / 256;
  k_zero<<<nb, 256, 0, stream>>>(rank, n);

  int jblocks = 40;
  int jchunk = (n + jblocks - 1) / jblocks;
  k_rank<<<dim3(nb, jblocks), 256, 0, stream>>>(scores, rank, n, jchunk);

  k_scatter<<<nb, 256, 0, stream>>>((const float4*)boxes, rank, sl, st_, sr, sb, sa, sidx, n);

  k_mask<<<dim3(nb, words), 256, 0, stream>>>(sl, st_, sr, sb, sa, mask, diag, n, wstride);

  k_scan<<<1, 64, 0, stream>>>(mask, diag, sidx, keep, n, wstride);

  int rpb = 10;
  int nj4 = (n + 3) >> 2;
  k_iou<<<dim3((nj4 + 255) / 256, (n + rpb - 1) / rpb), 256, 0, stream>>>((const float4*)boxes, out, n, rpb);
}